// Round 1
// baseline (789.653 us; speedup 1.0000x reference)
//
#include <hip/hip_runtime.h>

#define BN 4
#define CN 256
#define PN 4096

typedef __attribute__((ext_vector_type(8))) short short8;
typedef __attribute__((ext_vector_type(8))) unsigned short ushort8;
typedef __attribute__((ext_vector_type(4))) float f32x4;

__device__ __forceinline__ unsigned short f2bf(float f) {
  unsigned int u = __builtin_bit_cast(unsigned int, f);
  return (unsigned short)((u + 0x7fffu + ((u >> 16) & 1u)) >> 16);
}

// ---- kernel 1: mnorm[b*P+p] = max(sqrt(sum_c x^2), 1e-8)
__global__ void k_norm(const float* __restrict__ x, float* __restrict__ mnorm) {
  int t = blockIdx.x * 256 + threadIdx.x;  // 0 .. B*P-1
  int b = t >> 12, p = t & (PN - 1);
  const float* xp = x + (size_t)b * CN * PN + p;
  float s0 = 0.f, s1 = 0.f, s2 = 0.f, s3 = 0.f;
#pragma unroll 8
  for (int c = 0; c < CN; c += 4) {
    float v0 = xp[(size_t)(c + 0) * PN];
    float v1 = xp[(size_t)(c + 1) * PN];
    float v2 = xp[(size_t)(c + 2) * PN];
    float v3 = xp[(size_t)(c + 3) * PN];
    s0 += v0 * v0; s1 += v1 * v1; s2 += v2 * v2; s3 += v3 * v3;
  }
  mnorm[t] = fmaxf(sqrtf(s0 + s1 + s2 + s3), 1e-8f);
}

// ---- kernel 2: xnT[b][p][c] = bf16(x[b][c][p] / mnorm[b][p])   (LDS transpose)
__global__ void k_xnt(const float* __restrict__ x, const float* __restrict__ mnorm,
                      unsigned short* __restrict__ xnT) {
  __shared__ float tl[64][65];
  int b = blockIdx.z, c0 = blockIdx.x * 64, p0 = blockIdx.y * 64;
  int tid = threadIdx.x;
  int tp = tid & 63, tc = tid >> 6;
  float rn = 1.0f / mnorm[b * PN + p0 + tp];
  const float* xb = x + ((size_t)b * CN + c0) * PN + p0 + tp;
#pragma unroll
  for (int i = 0; i < 16; ++i) {
    int cl = tc * 16 + i;
    tl[tp][cl] = xb[(size_t)cl * PN] * rn;
  }
  __syncthreads();
#pragma unroll
  for (int pass = 0; pass < 2; ++pass) {
    int id = tid + pass * 256;
    int row = id >> 3, col = (id & 7) * 8;
    ushort8 o;
#pragma unroll
    for (int j = 0; j < 8; ++j) o[j] = f2bf(tl[row][col + j]);
    *(ushort8*)(xnT + ((size_t)(b * PN + p0 + row) * CN + c0 + col)) = o;
  }
}

// ---- kernel 3: gxv[b][c][q] = bf16( (W @ xn)[c][q] * mnorm[q] + bias[c] )
__global__ void k_gx(const float* __restrict__ Wm, const float* __restrict__ bias,
                     const unsigned short* __restrict__ xnT, const float* __restrict__ mnorm,
                     unsigned short* __restrict__ gxv) {
  int b = blockIdx.z;
  int m0 = blockIdx.y * 64;
  int q0 = blockIdx.x * 64;
  int tid = threadIdx.x;
  int wave = tid >> 6, lane = tid & 63;
  int lr = lane & 15, g = lane >> 4;

  // A fragments: rows of W (fp32 -> bf16 on the fly)
  short8 af[8];
  {
    const float* wr = Wm + (size_t)(m0 + wave * 16 + lr) * CN;
#pragma unroll
    for (int k = 0; k < 8; ++k) {
      const float* ap = wr + k * 32 + g * 8;
      short8 a;
#pragma unroll
      for (int j = 0; j < 8; ++j) a[j] = (short)f2bf(ap[j]);
      af[k] = a;
    }
  }
  f32x4 acc[4];
#pragma unroll
  for (int n = 0; n < 4; ++n) acc[n] = (f32x4){0.f, 0.f, 0.f, 0.f};

  const unsigned short* xb = xnT + (size_t)b * PN * CN;
#pragma unroll
  for (int n = 0; n < 4; ++n) {
    const unsigned short* bp = xb + (size_t)(q0 + n * 16 + lr) * CN + g * 8;
#pragma unroll
    for (int k = 0; k < 8; ++k) {
      short8 bf = *(const short8*)(bp + k * 32);
      acc[n] = __builtin_amdgcn_mfma_f32_16x16x32_bf16(af[k], bf, acc[n], 0, 0, 0);
    }
  }
  // epilogue: scale by mnorm[q], add bias[c], write bf16 [B][C][P]
#pragma unroll
  for (int n = 0; n < 4; ++n) {
    int q = q0 + n * 16 + lr;
    float mn = mnorm[b * PN + q];
#pragma unroll
    for (int i = 0; i < 4; ++i) {
      int c = m0 + wave * 16 + g * 4 + i;
      float v = acc[n][i] * mn + bias[c];
      gxv[((size_t)b * CN + c) * PN + q] = f2bf(v);
    }
  }
}

// ---- kernel 4: fused  y^T[p][c] = sum_q relu(xn_p . xn_q)^2 * gx[c][q]
__launch_bounds__(256)
__global__ void k_attn(const unsigned short* __restrict__ xnT,
                       const unsigned short* __restrict__ gxv,
                       float* __restrict__ out) {
  __shared__ __align__(16) unsigned short s_all[4][16 * 72];  // per-wave S tile (bf16, pad 8)
  __shared__ __align__(16) float y_all[4][16 * 130];          // per-wave epilogue staging
  int b = blockIdx.y;
  int p0 = blockIdx.x * 64;
  int tid = threadIdx.x;
  int wave = tid >> 6, lane = tid & 63;
  int lr = lane & 15, g = lane >> 4;
  unsigned short* sl = s_all[wave];
  float* yl = y_all[wave];
  int pw = p0 + wave * 16;
  const unsigned short* xb = xnT + (size_t)b * PN * CN;
  const unsigned short* vb = gxv + (size_t)b * CN * PN;

  // hoist Q (16 rows x 256 ch) into registers: 8 A-fragments
  short8 qf[8];
  {
    const unsigned short* qp = xb + (size_t)(pw + lr) * CN + g * 8;
#pragma unroll
    for (int k = 0; k < 8; ++k) qf[k] = *(const short8*)(qp + k * 32);
  }

  f32x4 yacc[16];
#pragma unroll
  for (int n = 0; n < 16; ++n) yacc[n] = (f32x4){0.f, 0.f, 0.f, 0.f};

  for (int qt = 0; qt < PN / 64; ++qt) {
    int q0 = qt * 64;
    // --- QK^T: S[16 p][64 q], K = 256
    f32x4 sacc[4];
#pragma unroll
    for (int n = 0; n < 4; ++n) sacc[n] = (f32x4){0.f, 0.f, 0.f, 0.f};
#pragma unroll
    for (int n = 0; n < 4; ++n) {
      const unsigned short* bp = xb + (size_t)(q0 + n * 16 + lr) * CN + g * 8;
#pragma unroll
      for (int k = 0; k < 8; ++k) {
        short8 bf = *(const short8*)(bp + k * 32);
        sacc[n] = __builtin_amdgcn_mfma_f32_16x16x32_bf16(qf[k], bf, sacc[n], 0, 0, 0);
      }
    }
    // --- relu^2 -> bf16 -> wave-private LDS  (D layout: row=4g+i, col=lr)
#pragma unroll
    for (int n = 0; n < 4; ++n) {
#pragma unroll
      for (int i = 0; i < 4; ++i) {
        float v = fmaxf(sacc[n][i], 0.f);
        v = v * v;
        sl[(g * 4 + i) * 72 + n * 16 + lr] = f2bf(v);
      }
    }
    // --- PV: Y[16 p][256 c] += S[16 x 64] @ V[64 q][256 c]
#pragma unroll
    for (int kk = 0; kk < 2; ++kk) {
      short8 a = *(const short8*)(sl + lr * 72 + kk * 32 + g * 8);
      const unsigned short* vp = vb + (size_t)lr * PN + q0 + kk * 32 + g * 8;
#pragma unroll
      for (int n2 = 0; n2 < 16; ++n2) {
        short8 bf = *(const short8*)(vp + (size_t)(n2 * 16) * PN);
        yacc[n2] = __builtin_amdgcn_mfma_f32_16x16x32_bf16(a, bf, yacc[n2], 0, 0, 0);
      }
    }
  }

  // ---- epilogue: stage per-wave 16 x 256 f32 tile via LDS for coalesced stores
  float* ob = out + (size_t)b * CN * PN + pw;
#pragma unroll
  for (int h = 0; h < 2; ++h) {
#pragma unroll
    for (int n2 = 0; n2 < 8; ++n2) {
#pragma unroll
      for (int i = 0; i < 4; ++i)
        yl[(g * 4 + i) * 130 + n2 * 16 + lr] = yacc[h * 8 + n2][i];
    }
#pragma unroll
    for (int cc = 0; cc < 32; ++cc) {
      int cl = cc * 4 + g;
      int c = h * 128 + cl;
      ob[(size_t)c * PN + lr] = yl[lr * 130 + cl];
    }
  }
}

extern "C" void kernel_launch(void* const* d_in, const int* in_sizes, int n_in,
                              void* d_out, int out_size, void* d_ws, size_t ws_size,
                              hipStream_t stream) {
  const float* x = (const float*)d_in[0];
  const float* Wm = (const float*)d_in[1];
  const float* bias = (const float*)d_in[2];
  float* out = (float*)d_out;

  char* ws = (char*)d_ws;
  unsigned short* xnT = (unsigned short*)ws;                        // 8 MB  [B][P][C] bf16
  unsigned short* gxv = (unsigned short*)(ws + (size_t)8388608);    // 8 MB  [B][C][P] bf16
  float* mnorm = (float*)(ws + (size_t)16777216);                   // 64 KB [B][P] f32

  k_norm<<<dim3((BN * PN) / 256), dim3(256), 0, stream>>>(x, mnorm);
  k_xnt<<<dim3(CN / 64, PN / 64, BN), dim3(256), 0, stream>>>(x, mnorm, xnT);
  k_gx<<<dim3(PN / 64, CN / 64, BN), dim3(256), 0, stream>>>(Wm, bias, xnT, mnorm, gxv);
  k_attn<<<dim3(PN / 64, BN), dim3(256), 0, stream>>>(xnT, gxv, out);
}

// Round 2
// 155.199 us; speedup vs baseline: 5.0880x; 5.0880x over previous
//
#include <hip/hip_runtime.h>

#define BN 4
#define CN 256
#define PN 4096
#define QT 32
#define NT 64          // q-range 2048 / QT
#define KSTR 264       // K-tile LDS row stride (bf16 elems), 528B = 16B-aligned, ~2-way banks
#define VSTR 40        // V-tile LDS row stride, 80B
#define SSTR 40

typedef __attribute__((ext_vector_type(8))) short short8;
typedef __attribute__((ext_vector_type(8))) unsigned short ushort8;
typedef __attribute__((ext_vector_type(4))) float f32x4;

__device__ __forceinline__ unsigned short f2bf(float f) {
  unsigned int u = __builtin_bit_cast(unsigned int, f);
  return (unsigned short)((u + 0x7fffu + ((u >> 16) & 1u)) >> 16);
}

// ---- fused: per 64-pixel block, compute channel norm + write xnT[b][p][c] bf16
__global__ __launch_bounds__(256) void k_nx(const float* __restrict__ x,
                                            float* __restrict__ mnorm,
                                            unsigned short* __restrict__ xnT) {
  __shared__ unsigned short tl[64 * KSTR];  // [64 p][264 c] bf16
  __shared__ float red[4][64];
  const int b = blockIdx.y, p0 = blockIdx.x * 64;
  const int tid = threadIdx.x;
  const int tp = tid & 63, cg = tid >> 6;
  const float* xp = x + ((size_t)b * CN + cg * 64) * PN + p0 + tp;
  float v[64];
  float ss = 0.f;
#pragma unroll
  for (int i = 0; i < 64; ++i) {
    v[i] = xp[(size_t)i * PN];
    ss += v[i] * v[i];
  }
  red[cg][tp] = ss;
  __syncthreads();
  float nrm = sqrtf(red[0][tp] + red[1][tp] + red[2][tp] + red[3][tp]);
  float mn = fmaxf(nrm, 1e-8f);
  float rn = 1.f / mn;
  if (cg == 0) mnorm[b * PN + p0 + tp] = mn;
  // packed bf16x2 writes into transposed LDS tile
  unsigned int* tl32 = (unsigned int*)tl;
#pragma unroll
  for (int j = 0; j < 32; ++j) {
    unsigned int w = (unsigned int)f2bf(v[2 * j] * rn) |
                     ((unsigned int)f2bf(v[2 * j + 1] * rn) << 16);
    tl32[tp * (KSTR / 2) + cg * 32 + j] = w;
  }
  __syncthreads();
  // coalesced store: per instr, 16 rows x 64B contiguous
  unsigned short* xd = xnT + ((size_t)b * PN + p0) * CN;
  const int row = tid >> 2, qc = tid & 3;
#pragma unroll
  for (int i = 0; i < 8; ++i) {
    ushort8 o = *(const ushort8*)(tl + row * KSTR + i * 32 + qc * 8);
    *(ushort8*)(xd + (size_t)row * CN + i * 32 + qc * 8) = o;
  }
}

// ---- gxv[b][c][q] = bf16( (W @ xn)[c][q] * mnorm[q] + bias[c] )
__global__ void k_gx(const float* __restrict__ Wm, const float* __restrict__ bias,
                     const unsigned short* __restrict__ xnT, const float* __restrict__ mnorm,
                     unsigned short* __restrict__ gxv) {
  int b = blockIdx.z;
  int m0 = blockIdx.y * 64;
  int q0 = blockIdx.x * 64;
  int tid = threadIdx.x;
  int wave = tid >> 6, lane = tid & 63;
  int lr = lane & 15, g = lane >> 4;

  short8 af[8];
  {
    const float* wr = Wm + (size_t)(m0 + wave * 16 + lr) * CN;
#pragma unroll
    for (int k = 0; k < 8; ++k) {
      const float* ap = wr + k * 32 + g * 8;
      short8 a;
#pragma unroll
      for (int j = 0; j < 8; ++j) a[j] = (short)f2bf(ap[j]);
      af[k] = a;
    }
  }
  f32x4 acc[4];
#pragma unroll
  for (int n = 0; n < 4; ++n) acc[n] = (f32x4){0.f, 0.f, 0.f, 0.f};

  const unsigned short* xb = xnT + (size_t)b * PN * CN;
#pragma unroll
  for (int n = 0; n < 4; ++n) {
    const unsigned short* bp = xb + (size_t)(q0 + n * 16 + lr) * CN + g * 8;
#pragma unroll
    for (int k = 0; k < 8; ++k) {
      short8 bf = *(const short8*)(bp + k * 32);
      acc[n] = __builtin_amdgcn_mfma_f32_16x16x32_bf16(af[k], bf, acc[n], 0, 0, 0);
    }
  }
#pragma unroll
  for (int n = 0; n < 4; ++n) {
    int q = q0 + n * 16 + lr;
    float mn = mnorm[b * PN + q];
#pragma unroll
    for (int i = 0; i < 4; ++i) {
      int c = m0 + wave * 16 + g * 4 + i;
      float v = acc[n][i] * mn + bias[c];
      gxv[((size_t)b * CN + c) * PN + q] = f2bf(v);
    }
  }
}

// ---- fused attention: y^T[p][c] = sum_q relu(xn_p.xn_q)^2 * gx[c][q], q-split 2
extern __shared__ char smem[];

__global__ __launch_bounds__(128, 1) void k_attn(const unsigned short* __restrict__ xnT,
                                                 const unsigned short* __restrict__ gxv,
                                                 float* __restrict__ out0,
                                                 float* __restrict__ out1) {
  const int fid = blockIdx.x;          // XCD-swizzled: b=(fid>>1)&3, qs=fid&1, pblk=fid>>3
  const int b = (fid >> 1) & 3;
  const int qs = fid & 1;
  const int pblk = fid >> 3;
  const int tid = threadIdx.x;
  const int wave = tid >> 6, lane = tid & 63, lr = lane & 15, g = lane >> 4;
  const int qbase = qs * (PN / 2);
  const int p0 = pblk * 64 + wave * 32;

  const unsigned short* xb = xnT + (size_t)b * PN * CN;
  const unsigned short* vb = gxv + (size_t)b * CN * PN;

  // LDS: K dbuf 2x16896, V dbuf 2x20480, S per-wave 2x2560 -> 79872 B
  unsigned short* Sb = (unsigned short*)(smem + 74752) + wave * 1280;

  // hoist Q fragments (32 p-rows x 256 c)
  short8 qf[2][8];
#pragma unroll
  for (int mt = 0; mt < 2; ++mt) {
    const unsigned short* qp = xb + (size_t)(p0 + mt * 16 + lr) * CN + g * 8;
#pragma unroll
    for (int k = 0; k < 8; ++k) qf[mt][k] = *(const short8*)(qp + k * 32);
  }

  f32x4 yacc[2][16];
#pragma unroll
  for (int mt = 0; mt < 2; ++mt)
#pragma unroll
    for (int n = 0; n < 16; ++n) yacc[mt][n] = (f32x4){0.f, 0.f, 0.f, 0.f};

  const int krow = tid >> 5, kcol = (tid & 31) * 8;  // K stage: +pass*4 rows
  const int vrow = tid >> 2, vcol = (tid & 3) * 8;   // V stage: +pass*32 rows

  short8 rk[8], rv[8];

  auto stage_load = [&](int t) {
    const int q0 = qbase + t * QT;
    const unsigned short* kg = xb + (size_t)q0 * CN;
#pragma unroll
    for (int i = 0; i < 8; ++i)
      rk[i] = *(const short8*)(kg + (size_t)(i * 4 + krow) * CN + kcol);
    const unsigned short* vg = vb + q0;
#pragma unroll
    for (int i = 0; i < 8; ++i)
      rv[i] = *(const short8*)(vg + (size_t)(i * 32 + vrow) * PN + vcol);
  };
  auto stage_write = [&](int buf) {
    unsigned short* kd = (unsigned short*)(smem + buf * 16896);
    unsigned short* vd = (unsigned short*)(smem + 33792 + buf * 20480);
#pragma unroll
    for (int i = 0; i < 8; ++i)
      *(short8*)(kd + (i * 4 + krow) * KSTR + kcol) = rk[i];
#pragma unroll
    for (int i = 0; i < 8; ++i)
      *(short8*)(vd + (i * 32 + vrow) * VSTR + vcol) = rv[i];
  };
  auto compute = [&](int buf) {
    const unsigned short* kd = (const unsigned short*)(smem + buf * 16896);
    const unsigned short* vd = (const unsigned short*)(smem + 33792 + buf * 20480);
    f32x4 sacc[2][2];
#pragma unroll
    for (int mt = 0; mt < 2; ++mt)
#pragma unroll
      for (int nt = 0; nt < 2; ++nt) sacc[mt][nt] = (f32x4){0.f, 0.f, 0.f, 0.f};
#pragma unroll
    for (int nt = 0; nt < 2; ++nt) {
      const unsigned short* kp = kd + (nt * 16 + lr) * KSTR + g * 8;
#pragma unroll
      for (int k = 0; k < 8; ++k) {
        short8 kf = *(const short8*)(kp + k * 32);
        sacc[0][nt] = __builtin_amdgcn_mfma_f32_16x16x32_bf16(qf[0][k], kf, sacc[0][nt], 0, 0, 0);
        sacc[1][nt] = __builtin_amdgcn_mfma_f32_16x16x32_bf16(qf[1][k], kf, sacc[1][nt], 0, 0, 0);
      }
    }
    // relu^2 -> bf16 -> wave-private S tile
#pragma unroll
    for (int mt = 0; mt < 2; ++mt)
#pragma unroll
      for (int nt = 0; nt < 2; ++nt)
#pragma unroll
        for (int i = 0; i < 4; ++i) {
          float v = fmaxf(sacc[mt][nt][i], 0.f);
          v = v * v;
          Sb[(mt * 16 + g * 4 + i) * SSTR + nt * 16 + lr] = f2bf(v);
        }
    short8 pa[2];
#pragma unroll
    for (int mt = 0; mt < 2; ++mt)
      pa[mt] = *(const short8*)(Sb + (mt * 16 + lr) * SSTR + g * 8);
#pragma unroll
    for (int n2 = 0; n2 < 16; ++n2) {
      short8 vf = *(const short8*)(vd + (n2 * 16 + lr) * VSTR + g * 8);
      yacc[0][n2] = __builtin_amdgcn_mfma_f32_16x16x32_bf16(pa[0], vf, yacc[0][n2], 0, 0, 0);
      yacc[1][n2] = __builtin_amdgcn_mfma_f32_16x16x32_bf16(pa[1], vf, yacc[1][n2], 0, 0, 0);
    }
  };

  // pipeline: loads 2 tiles ahead, writes 1 ahead, one barrier per tile
  stage_load(0);
  stage_write(0);
  stage_load(1);
  __syncthreads();
  for (int t = 0; t < NT; ++t) {
    const int cur = t & 1;
    if (t + 1 < NT) {
      stage_write(cur ^ 1);
      if (t + 2 < NT) stage_load(t + 2);
    }
    compute(cur);
    __syncthreads();
  }

  // epilogue: stage 64c x 64p f32 chunks via LDS for coalesced [c][p] stores
  float* dst = (qs == 0 ? out0 : out1) + (size_t)b * CN * PN + pblk * 64;
  float* ylds = (float*)smem;  // [64][68]
  const int cl = tid >> 1, ph = tid & 1;
#pragma unroll
  for (int ch = 0; ch < 4; ++ch) {
    __syncthreads();
#pragma unroll
    for (int mt = 0; mt < 2; ++mt)
#pragma unroll
      for (int nn = 0; nn < 4; ++nn)
#pragma unroll
        for (int i = 0; i < 4; ++i)
          ylds[(wave * 32 + mt * 16 + g * 4 + i) * 68 + nn * 16 + lr] = yacc[mt][ch * 4 + nn][i];
    __syncthreads();
#pragma unroll
    for (int pp = 0; pp < 8; ++pp) {
      float4 v;
      v.x = ylds[(ph * 32 + pp * 4 + 0) * 68 + cl];
      v.y = ylds[(ph * 32 + pp * 4 + 1) * 68 + cl];
      v.z = ylds[(ph * 32 + pp * 4 + 2) * 68 + cl];
      v.w = ylds[(ph * 32 + pp * 4 + 3) * 68 + cl];
      *(float4*)(dst + (size_t)(ch * 64 + cl) * PN + ph * 32 + pp * 4) = v;
    }
  }
}

// ---- final reduction: out += ypart
__global__ void k_add(float* __restrict__ o, const float* __restrict__ p, int n4) {
  int i = blockIdx.x * blockDim.x + threadIdx.x;
  int stride = gridDim.x * blockDim.x;
  float4* o4 = (float4*)o;
  const float4* p4 = (const float4*)p;
  for (; i < n4; i += stride) {
    float4 a = o4[i];
    float4 c = p4[i];
    a.x += c.x; a.y += c.y; a.z += c.z; a.w += c.w;
    o4[i] = a;
  }
}

extern "C" void kernel_launch(void* const* d_in, const int* in_sizes, int n_in,
                              void* d_out, int out_size, void* d_ws, size_t ws_size,
                              hipStream_t stream) {
  const float* x = (const float*)d_in[0];
  const float* Wm = (const float*)d_in[1];
  const float* bias = (const float*)d_in[2];
  float* out = (float*)d_out;

  char* ws = (char*)d_ws;
  unsigned short* xnT = (unsigned short*)ws;                           // 8 MB  [B][P][C] bf16
  unsigned short* gxv = (unsigned short*)(ws + (size_t)8388608);       // 8 MB  [B][C][P] bf16
  float* mnorm = (float*)(ws + (size_t)16777216);                      // 64 KB [B][P] f32
  float* ypart = (float*)(ws + (size_t)16842752);                      // 16 MB [B][C][P] f32

  hipFuncSetAttribute((const void*)k_attn, hipFuncAttributeMaxDynamicSharedMemorySize, 79872);

  k_nx<<<dim3(PN / 64, BN), 256, 0, stream>>>(x, mnorm, xnT);
  k_gx<<<dim3(PN / 64, CN / 64, BN), 256, 0, stream>>>(Wm, bias, xnT, mnorm, gxv);
  k_attn<<<dim3(512), 128, 79872, stream>>>(xnT, gxv, out, ypart);
  k_add<<<dim3(1024), 256, 0, stream>>>(out, ypart, BN * CN * PN / 4);
}

// Round 3
// 148.163 us; speedup vs baseline: 5.3296x; 1.0475x over previous
//
#include <hip/hip_runtime.h>

#define BN 4
#define CN 256
#define PN 4096
#define QT 32
#define TSTR 264

typedef __attribute__((ext_vector_type(8))) short short8;
typedef __attribute__((ext_vector_type(8))) unsigned short ushort8;
typedef __attribute__((ext_vector_type(4))) float f32x4;
typedef unsigned int u32;

__device__ __forceinline__ unsigned short f2bf(float f) {
  u32 u = __builtin_bit_cast(u32, f);
  return (unsigned short)((u + 0x7fffu + ((u >> 16) & 1u)) >> 16);
}

__device__ __forceinline__ void async_copy16(const void* g, void* l) {
  __builtin_amdgcn_global_load_lds((const __attribute__((address_space(1))) u32*)g,
                                   (__attribute__((address_space(3))) u32*)l, 16, 0, 0);
}

// ---- fused: per 64-pixel block, compute channel norm + write xnT[b][p][c] bf16
__global__ __launch_bounds__(256) void k_nx(const float* __restrict__ x,
                                            float* __restrict__ mnorm,
                                            unsigned short* __restrict__ xnT) {
  __shared__ unsigned short tl[64 * TSTR];
  __shared__ float red[4][64];
  const int b = blockIdx.y, p0 = blockIdx.x * 64;
  const int tid = threadIdx.x;
  const int tp = tid & 63, cg = tid >> 6;
  const float* xp = x + ((size_t)b * CN + cg * 64) * PN + p0 + tp;
  float v[64];
  float ss = 0.f;
#pragma unroll
  for (int i = 0; i < 64; ++i) {
    v[i] = xp[(size_t)i * PN];
    ss += v[i] * v[i];
  }
  red[cg][tp] = ss;
  __syncthreads();
  float nrm = sqrtf(red[0][tp] + red[1][tp] + red[2][tp] + red[3][tp]);
  float mn = fmaxf(nrm, 1e-8f);
  float rn = 1.f / mn;
  if (cg == 0) mnorm[b * PN + p0 + tp] = mn;
  unsigned int* tl32 = (unsigned int*)tl;
#pragma unroll
  for (int j = 0; j < 32; ++j) {
    unsigned int w = (unsigned int)f2bf(v[2 * j] * rn) |
                     ((unsigned int)f2bf(v[2 * j + 1] * rn) << 16);
    tl32[tp * (TSTR / 2) + cg * 32 + j] = w;
  }
  __syncthreads();
  unsigned short* xd = xnT + ((size_t)b * PN + p0) * CN;
  const int row = tid >> 2, qc = tid & 3;
#pragma unroll
  for (int i = 0; i < 8; ++i) {
    ushort8 o = *(const ushort8*)(tl + row * TSTR + i * 32 + qc * 8);
    *(ushort8*)(xd + (size_t)row * CN + i * 32 + qc * 8) = o;
  }
}

// ---- gxv[b][c][q] = bf16( (W @ xn)[c][q] * mnorm[q] + bias[c] )
__global__ void k_gx(const float* __restrict__ Wm, const float* __restrict__ bias,
                     const unsigned short* __restrict__ xnT, const float* __restrict__ mnorm,
                     unsigned short* __restrict__ gxv) {
  int b = blockIdx.z;
  int m0 = blockIdx.y * 64;
  int q0 = blockIdx.x * 64;
  int tid = threadIdx.x;
  int wave = tid >> 6, lane = tid & 63;
  int lr = lane & 15, g = lane >> 4;

  short8 af[8];
  {
    const float* wr = Wm + (size_t)(m0 + wave * 16 + lr) * CN;
#pragma unroll
    for (int k = 0; k < 8; ++k) {
      const float* ap = wr + k * 32 + g * 8;
      short8 a;
#pragma unroll
      for (int j = 0; j < 8; ++j) a[j] = (short)f2bf(ap[j]);
      af[k] = a;
    }
  }
  f32x4 acc[4];
#pragma unroll
  for (int n = 0; n < 4; ++n) acc[n] = (f32x4){0.f, 0.f, 0.f, 0.f};

  const unsigned short* xb = xnT + (size_t)b * PN * CN;
#pragma unroll
  for (int n = 0; n < 4; ++n) {
    const unsigned short* bp = xb + (size_t)(q0 + n * 16 + lr) * CN + g * 8;
#pragma unroll
    for (int k = 0; k < 8; ++k) {
      short8 bf = *(const short8*)(bp + k * 32);
      acc[n] = __builtin_amdgcn_mfma_f32_16x16x32_bf16(af[k], bf, acc[n], 0, 0, 0);
    }
  }
#pragma unroll
  for (int n = 0; n < 4; ++n) {
    int q = q0 + n * 16 + lr;
    float mn = mnorm[b * PN + q];
#pragma unroll
    for (int i = 0; i < 4; ++i) {
      int c = m0 + wave * 16 + g * 4 + i;
      float v = acc[n][i] * mn + bias[c];
      gxv[((size_t)b * CN + c) * PN + q] = f2bf(v);
    }
  }
}

// ---- fused attention: y^T[p][c] = sum_q relu(xn_p.xn_q)^2 * gx[c][q]
// M = MT*16 rows per wave, 2 waves/WG, q-split 2^lq across WGs.
// LDS: K/V double buffer (2x32KB, XOR-swizzled), S per-wave 4KB -> 73728 B.
extern __shared__ char smem[];

template <int MT>
__global__ __launch_bounds__(128, 1) void k_attn(const unsigned short* __restrict__ xnT,
                                                 const unsigned short* __restrict__ gxv,
                                                 float* __restrict__ d0, float* __restrict__ d1,
                                                 float* __restrict__ d2, float* __restrict__ d3,
                                                 int lq, int ntiles) {
  const int fid = blockIdx.x;
  const int b = fid & 3;
  const int qs = (fid >> 2) & ((1 << lq) - 1);
  const int pblk = fid >> (2 + lq);
  const int tid = threadIdx.x;
  const int wave = tid >> 6, lane = tid & 63, lr = lane & 15, g = lane >> 4;
  const int qbase = qs * (PN >> lq);
  const int p0 = pblk * (MT * 32) + wave * (MT * 16);
  float* dst = (qs == 0) ? d0 : (qs == 1) ? d1 : (qs == 2) ? d2 : d3;

  const char* xbc = (const char*)(xnT + (size_t)b * PN * CN);
  const char* vbc = (const char*)(gxv + (size_t)b * CN * PN);

  // lane-constant read offset for V/S fragments: ((r&15)<<4) full-byte XOR, r%16 == lr
  const int vro = (lr * 64 + g * 16) ^ (lr << 4);
  char* Sme = smem + 65536 + wave * 4096;

  // staging source offsets (lane-constant, inverse-swizzled)
  int koff[8], vofs[8];
#pragma unroll
  for (int j = 0; j < 8; ++j) {
    int rk = 16 * wave + 2 * j + (lane >> 5);
    koff[j] = rk * 512 + (((lane & 31) << 4) ^ ((rk & 15) << 4));
    int dlin = (128 * wave + 16 * j) * 64 + lane * 16;  // linear dest byte in V tile
    int hi = dlin >> 8;
    int rv = (hi << 2) | (((dlin >> 6) & 3) ^ (hi & 3));
    int sg = ((dlin >> 4) & 3) ^ (rv & 3);
    vofs[j] = rv * (PN * 2) + sg * 16;
  }

  // hoist Q fragments (MT*16 rows x 256 ch)
  short8 qf[MT][8];
#pragma unroll
  for (int mt = 0; mt < MT; ++mt) {
    const char* qp = xbc + (size_t)(p0 + mt * 16 + lr) * 512 + g * 16;
#pragma unroll
    for (int k = 0; k < 8; ++k) qf[mt][k] = *(const short8*)(qp + k * 64);
  }

  f32x4 yacc[MT][16];
#pragma unroll
  for (int mt = 0; mt < MT; ++mt)
#pragma unroll
    for (int n = 0; n < 16; ++n) yacc[mt][n] = (f32x4){0.f, 0.f, 0.f, 0.f};

  auto issue_L = [&](int t) {
    const int q0 = qbase + t * QT;
    char* kb = smem + (t & 1) * 32768;
    char* vb = kb + 16384;
    const char* kg = xbc + (size_t)q0 * 512;
    const char* vg = vbc + (size_t)q0 * 2;
#pragma unroll
    for (int j = 0; j < 8; ++j) {
      async_copy16(kg + koff[j], kb + (16 * wave + 2 * j) * 512);
      async_copy16(vg + vofs[j], vb + (128 * wave + 16 * j) * 64);
    }
  };

  auto compute = [&](int buf) {
    const char* kb = smem + buf * 32768;
    const char* vb = kb + 16384;
    f32x4 sacc[MT][2];
#pragma unroll
    for (int mt = 0; mt < MT; ++mt)
#pragma unroll
      for (int nt = 0; nt < 2; ++nt) sacc[mt][nt] = (f32x4){0.f, 0.f, 0.f, 0.f};
#pragma unroll
    for (int nt = 0; nt < 2; ++nt)
#pragma unroll
      for (int k = 0; k < 8; ++k) {
        short8 kf = *(const short8*)(kb + nt * 8192 + lr * 512 +
                                     (((k << 6) | (g << 4)) ^ (lr << 4)));
#pragma unroll
        for (int mt = 0; mt < MT; ++mt)
          sacc[mt][nt] = __builtin_amdgcn_mfma_f32_16x16x32_bf16(qf[mt][k], kf, sacc[mt][nt], 0, 0, 0);
      }
    // relu^2 -> bf16 -> wave-private S (XOR-swizzled rows)
#pragma unroll
    for (int mt = 0; mt < MT; ++mt)
#pragma unroll
      for (int nt = 0; nt < 2; ++nt)
#pragma unroll
        for (int i = 0; i < 4; ++i) {
          float v = fmaxf(sacc[mt][nt][i], 0.f);
          v *= v;
          int sb = ((mt * 16 + g * 4 + i) * 64 + nt * 32 + lr * 2) ^ ((g * 4 + i) << 4);
          *(unsigned short*)(Sme + sb) = f2bf(v);
        }
    short8 pa[MT];
#pragma unroll
    for (int mt = 0; mt < MT; ++mt) pa[mt] = *(const short8*)(Sme + mt * 1024 + vro);
#pragma unroll
    for (int n2 = 0; n2 < 16; ++n2) {
      short8 vf = *(const short8*)(vb + n2 * 1024 + vro);
#pragma unroll
      for (int mt = 0; mt < MT; ++mt)
        yacc[mt][n2] = __builtin_amdgcn_mfma_f32_16x16x32_bf16(pa[mt], vf, yacc[mt][n2], 0, 0, 0);
    }
  };

  // pipeline: dbuf, loads for t+1 issued right after barrier of t (latency covered by compute body)
  issue_L(0);
  for (int t = 0; t < ntiles; ++t) {
    asm volatile("s_waitcnt vmcnt(0)" ::: "memory");
    __builtin_amdgcn_s_barrier();
    if (t + 1 < ntiles) issue_L(t + 1);
    compute(t & 1);
  }

  // ---- epilogue: per-wave LDS staging (reuse K/V region) for coalesced [c][p] stores
  asm volatile("s_waitcnt lgkmcnt(0)" ::: "memory");
  __builtin_amdgcn_s_barrier();
  constexpr int PW = MT * 16;
  constexpr int LPR = PW / 4;   // lanes per c-row on readout
  constexpr int RPI = 64 / LPR; // c-rows per read instr
  float* yl = (float*)(smem + wave * 17408);
  const int rl = lane / LPR;
  const int pc = (lane % LPR) * 4;
#pragma unroll
  for (int cc = 0; cc < 4; ++cc) {
#pragma unroll
    for (int nn = 0; nn < 4; ++nn)
#pragma unroll
      for (int mt = 0; mt < MT; ++mt)
#pragma unroll
        for (int i = 0; i < 4; ++i)
          yl[(nn * 16 + lr) * 68 + mt * 16 + g * 4 + i] = yacc[mt][cc * 4 + nn][i];
#pragma unroll
    for (int i2 = 0; i2 < 64 / RPI; ++i2) {
      int cl = i2 * RPI + rl;
      float4 v = *(const float4*)(yl + cl * 68 + pc);
      *(float4*)(dst + ((size_t)b * CN + cc * 64 + cl) * PN + p0 + pc) = v;
    }
  }
}

// ---- final reduction: out += sum of partials
__global__ void k_add(float* __restrict__ o, const float* __restrict__ a,
                      const float* __restrict__ bb, const float* __restrict__ c,
                      int np, int n4) {
  int i = blockIdx.x * blockDim.x + threadIdx.x;
  int stride = gridDim.x * blockDim.x;
  float4* o4 = (float4*)o;
  const float4* a4 = (const float4*)a;
  const float4* b4 = (const float4*)bb;
  const float4* c4 = (const float4*)c;
  for (; i < n4; i += stride) {
    float4 r = o4[i];
    float4 va = a4[i];
    r.x += va.x; r.y += va.y; r.z += va.z; r.w += va.w;
    if (np > 1) {
      float4 vb = b4[i];
      r.x += vb.x; r.y += vb.y; r.z += vb.z; r.w += vb.w;
      float4 vc = c4[i];
      r.x += vc.x; r.y += vc.y; r.z += vc.z; r.w += vc.w;
    }
    o4[i] = r;
  }
}

extern "C" void kernel_launch(void* const* d_in, const int* in_sizes, int n_in,
                              void* d_out, int out_size, void* d_ws, size_t ws_size,
                              hipStream_t stream) {
  const float* x = (const float*)d_in[0];
  const float* Wm = (const float*)d_in[1];
  const float* bias = (const float*)d_in[2];
  float* out = (float*)d_out;

  char* ws = (char*)d_ws;
  unsigned short* xnT = (unsigned short*)ws;                        // 8 MB  [B][P][C] bf16
  unsigned short* gxv = (unsigned short*)(ws + (size_t)8388608);    // 8 MB  [B][C][P] bf16
  float* mnorm = (float*)(ws + (size_t)16777216);                   // 64 KB [B][P] f32
  float* yp0 = (float*)(ws + (size_t)16842752);                     // 16 MB partials x3
  float* yp1 = yp0 + 4194304;
  float* yp2 = yp1 + 4194304;
  const size_t need4 = 16842752ULL + 3ULL * 16777216ULL;

  hipFuncSetAttribute(reinterpret_cast<const void*>(k_attn<4>),
                      hipFuncAttributeMaxDynamicSharedMemorySize, 73728);
  hipFuncSetAttribute(reinterpret_cast<const void*>(k_attn<2>),
                      hipFuncAttributeMaxDynamicSharedMemorySize, 73728);

  k_nx<<<dim3(PN / 64, BN), 256, 0, stream>>>(x, mnorm, xnT);
  k_gx<<<dim3(PN / 64, CN / 64, BN), 256, 0, stream>>>(Wm, bias, xnT, mnorm, gxv);
  if (ws_size >= need4) {
    k_attn<4><<<dim3(512), 128, 73728, stream>>>(xnT, gxv, out, yp0, yp1, yp2, 2, 32);
    k_add<<<dim3(1024), 256, 0, stream>>>(out, yp0, yp1, yp2, 3, BN * CN * PN / 4);
  } else {
    k_attn<2><<<dim3(512), 128, 73728, stream>>>(xnT, gxv, out, yp0, yp0, yp0, 1, 64);
    k_add<<<dim3(1024), 256, 0, stream>>>(out, yp0, yp0, yp0, 1, BN * CN * PN / 4);
  }
}

// Round 5
// 122.903 us; speedup vs baseline: 6.4250x; 1.2055x over previous
//
#include <hip/hip_runtime.h>

#define BN 4
#define CN 256
#define PN 4096
#define QT 64
#define TSTR 264

typedef __attribute__((ext_vector_type(8))) short short8;
typedef __attribute__((ext_vector_type(8))) unsigned short ushort8;
typedef __attribute__((ext_vector_type(4))) float f32x4;
typedef unsigned int u32;

__device__ __forceinline__ unsigned short f2bf(float f) {
  u32 u = __builtin_bit_cast(u32, f);
  return (unsigned short)((u + 0x7fffu + ((u >> 16) & 1u)) >> 16);
}

__device__ __forceinline__ void async_copy16(const void* g, void* l) {
  __builtin_amdgcn_global_load_lds((const __attribute__((address_space(1))) u32*)g,
                                   (__attribute__((address_space(3))) u32*)l, 16, 0, 0);
}

// ---- fused: per 64-pixel block, compute channel norm + write xnT[b][p][c] bf16
__global__ __launch_bounds__(256) void k_nx(const float* __restrict__ x,
                                            float* __restrict__ mnorm,
                                            unsigned short* __restrict__ xnT) {
  __shared__ unsigned short tl[64 * TSTR];
  __shared__ float red[4][64];
  const int b = blockIdx.y, p0 = blockIdx.x * 64;
  const int tid = threadIdx.x;
  const int tp = tid & 63, cg = tid >> 6;
  const float* xp = x + ((size_t)b * CN + cg * 64) * PN + p0 + tp;
  float v[64];
  float ss = 0.f;
#pragma unroll
  for (int i = 0; i < 64; ++i) {
    v[i] = xp[(size_t)i * PN];
    ss += v[i] * v[i];
  }
  red[cg][tp] = ss;
  __syncthreads();
  float nrm = sqrtf(red[0][tp] + red[1][tp] + red[2][tp] + red[3][tp]);
  float mn = fmaxf(nrm, 1e-8f);
  float rn = 1.f / mn;
  if (cg == 0) mnorm[b * PN + p0 + tp] = mn;
  unsigned int* tl32 = (unsigned int*)tl;
#pragma unroll
  for (int j = 0; j < 32; ++j) {
    unsigned int w = (unsigned int)f2bf(v[2 * j] * rn) |
                     ((unsigned int)f2bf(v[2 * j + 1] * rn) << 16);
    tl32[tp * (TSTR / 2) + cg * 32 + j] = w;
  }
  __syncthreads();
  unsigned short* xd = xnT + ((size_t)b * PN + p0) * CN;
  const int row = tid >> 2, qc = tid & 3;
#pragma unroll
  for (int i = 0; i < 8; ++i) {
    ushort8 o = *(const ushort8*)(tl + row * TSTR + i * 32 + qc * 8);
    *(ushort8*)(xd + (size_t)row * CN + i * 32 + qc * 8) = o;
  }
}

// ---- gxv[b][c][q] = bf16( (W @ xn)[c][q] * mnorm[q] + bias[c] )
__global__ void k_gx(const float* __restrict__ Wm, const float* __restrict__ bias,
                     const unsigned short* __restrict__ xnT, const float* __restrict__ mnorm,
                     unsigned short* __restrict__ gxv) {
  int b = blockIdx.z;
  int m0 = blockIdx.y * 64;
  int q0 = blockIdx.x * 64;
  int tid = threadIdx.x;
  int wave = tid >> 6, lane = tid & 63;
  int lr = lane & 15, g = lane >> 4;

  short8 af[8];
  {
    const float* wr = Wm + (size_t)(m0 + wave * 16 + lr) * CN;
#pragma unroll
    for (int k = 0; k < 8; ++k) {
      const float* ap = wr + k * 32 + g * 8;
      short8 a;
#pragma unroll
      for (int j = 0; j < 8; ++j) a[j] = (short)f2bf(ap[j]);
      af[k] = a;
    }
  }
  f32x4 acc[4];
#pragma unroll
  for (int n = 0; n < 4; ++n) acc[n] = (f32x4){0.f, 0.f, 0.f, 0.f};

  const unsigned short* xb = xnT + (size_t)b * PN * CN;
#pragma unroll
  for (int n = 0; n < 4; ++n) {
    const unsigned short* bp = xb + (size_t)(q0 + n * 16 + lr) * CN + g * 8;
#pragma unroll
    for (int k = 0; k < 8; ++k) {
      short8 bf = *(const short8*)(bp + k * 32);
      acc[n] = __builtin_amdgcn_mfma_f32_16x16x32_bf16(af[k], bf, acc[n], 0, 0, 0);
    }
  }
#pragma unroll
  for (int n = 0; n < 4; ++n) {
    int q = q0 + n * 16 + lr;
    float mn = mnorm[b * PN + q];
#pragma unroll
    for (int i = 0; i < 4; ++i) {
      int c = m0 + wave * 16 + g * 4 + i;
      float v = acc[n][i] * mn + bias[c];
      gxv[((size_t)b * CN + c) * PN + q] = f2bf(v);
    }
  }
}

// ---- fused attention: 8-wave WG, M=32 rows/wave (256/WG), QT=64, 160KB LDS.
// LDS: [0,64K)=buf0 (K 32K | V 32K), [64K,128K)=buf1, [128K,160K)=S (4K/wave).
extern __shared__ char smem[];

__global__ __launch_bounds__(512, 2) void k_attn(const unsigned short* __restrict__ xnT,
                                                 const unsigned short* __restrict__ gxv,
                                                 float* __restrict__ d0, float* __restrict__ d1,
                                                 float* __restrict__ d2, float* __restrict__ d3,
                                                 int lq, int ntiles) {
  const int fid = blockIdx.x;
  const int b = fid & 3;
  const int qs = (fid >> 2) & ((1 << lq) - 1);
  const int pblk = fid >> (2 + lq);
  const int tid = threadIdx.x;
  const int wave = tid >> 6, lane = tid & 63, lr = lane & 15, g = lane >> 4;
  const int qbase = qs * (PN >> lq);
  const int p0 = pblk * 256 + wave * 32;
  float* dst = (qs == 0) ? d0 : (qs == 1) ? d1 : (qs == 2) ? d2 : d3;

  const char* xbc = (const char*)xnT + (size_t)b * PN * 512;
  const char* vbc = (const char*)gxv + (size_t)b * CN * PN * 2;

  // DMA lane constants: K rows = q (512B), V rows = c (128B); inverse-swizzled src
  const int kr = tid >> 5, kcolb = (tid & 31) << 4;
  const int ksrc = kr * 512 + (kcolb ^ ((kr & 7) << 4));
  const int vc = tid >> 3, vcolb = (tid & 7) << 4;
  const int vsrc = vc * 8192 + (vcolb ^ ((vc & 7) << 4));
  const int ldst = tid * 16;
  const int swz = (lr & 7) << 4;

  // hoist Q fragments (32 p-rows x 256 ch)
  short8 qf[2][8];
#pragma unroll
  for (int mt = 0; mt < 2; ++mt) {
    const char* qp = xbc + (size_t)(p0 + mt * 16 + lr) * 512 + g * 16;
#pragma unroll
    for (int k = 0; k < 8; ++k) qf[mt][k] = *(const short8*)(qp + k * 64);
  }

  f32x4 yacc[2][16];
#pragma unroll
  for (int mt = 0; mt < 2; ++mt)
#pragma unroll
    for (int n = 0; n < 16; ++n) yacc[mt][n] = (f32x4){0.f, 0.f, 0.f, 0.f};

  auto issue_L = [&](int t) {
    char* kb = smem + (t & 1) * 65536;
    char* vb = kb + 32768;
    const char* kg = xbc + (size_t)(qbase + t * QT) * 512 + ksrc;
    const char* vg = vbc + (size_t)(qbase + t * QT) * 2 + vsrc;
#pragma unroll
    for (int j = 0; j < 4; ++j) async_copy16(kg + j * 8192, kb + ldst + j * 8192);
#pragma unroll
    for (int j = 0; j < 4; ++j) async_copy16(vg + j * 524288, vb + ldst + j * 8192);
  };

  char* Sme = smem + 131072 + wave * 4096;

  auto compute = [&](int buf) {
    const char* kb = smem + buf * 65536;
    const char* vb = kb + 32768;
    __builtin_amdgcn_s_setprio(1);
    // QK^T, one n-tile (16 q) at a time; S written per n-tile
#pragma unroll
    for (int nt = 0; nt < 4; ++nt) {
      f32x4 s0 = (f32x4){0.f, 0.f, 0.f, 0.f}, s1 = (f32x4){0.f, 0.f, 0.f, 0.f};
      const char* kp = kb + (nt * 16 + lr) * 512;
#pragma unroll
      for (int k = 0; k < 8; ++k) {
        short8 kf = *(const short8*)(kp + ((k * 64 + g * 16) ^ swz));
        s0 = __builtin_amdgcn_mfma_f32_16x16x32_bf16(qf[0][k], kf, s0, 0, 0, 0);
        s1 = __builtin_amdgcn_mfma_f32_16x16x32_bf16(qf[1][k], kf, s1, 0, 0, 0);
      }
#pragma unroll
      for (int i = 0; i < 4; ++i) {
        int r0 = g * 4 + i;
        float v0 = fmaxf(s0[i], 0.f);
        v0 *= v0;
        *(unsigned short*)(Sme + r0 * 128 + ((nt * 32 + lr * 2) ^ ((r0 & 7) << 4))) = f2bf(v0);
        int r1 = 16 + r0;
        float v1 = fmaxf(s1[i], 0.f);
        v1 *= v1;
        *(unsigned short*)(Sme + r1 * 128 + ((nt * 32 + lr * 2) ^ ((r1 & 7) << 4))) = f2bf(v1);
      }
    }
    // PV: Y[32 p][256 c] += S[32 x 64] @ V[64 q][256 c]
#pragma unroll
    for (int kk = 0; kk < 2; ++kk) {
      short8 pa0 = *(const short8*)(Sme + lr * 128 + ((kk * 64 + g * 16) ^ swz));
      short8 pa1 = *(const short8*)(Sme + (16 + lr) * 128 + ((kk * 64 + g * 16) ^ swz));
#pragma unroll
      for (int n2 = 0; n2 < 16; ++n2) {
        short8 vf = *(const short8*)(vb + (n2 * 16 + lr) * 128 + ((kk * 64 + g * 16) ^ swz));
        yacc[0][n2] = __builtin_amdgcn_mfma_f32_16x16x32_bf16(pa0, vf, yacc[0][n2], 0, 0, 0);
        yacc[1][n2] = __builtin_amdgcn_mfma_f32_16x16x32_bf16(pa1, vf, yacc[1][n2], 0, 0, 0);
      }
    }
    __builtin_amdgcn_s_setprio(0);
  };

  // pipeline: dbuf, issue t+1 after barrier of t; vmcnt wait covered by prior compute body
  issue_L(0);
  for (int t = 0; t < ntiles; ++t) {
    asm volatile("s_waitcnt vmcnt(0)" ::: "memory");
    __builtin_amdgcn_s_barrier();
    if (t + 1 < ntiles) issue_L(t + 1);
    compute(t & 1);
  }
  __builtin_amdgcn_s_barrier();

  // ---- epilogue: per-wave LDS transpose (16KB region each) for coalesced [c][p] stores
  // yacc[mt][n2][i] = y[p = p0 + mt*16 + g*4+i][c = n2*16 + lr]  (D: col=lane&15, row=(lane>>4)*4+i)
  // yl layout: [c_local 0..63][p_local 0..31], stride 33 floats.
  float* yl = (float*)(smem + wave * 16384);
  const int row8 = lane >> 3, p4 = (lane & 7) << 2;
#pragma unroll
  for (int cc = 0; cc < 4; ++cc) {
#pragma unroll
    for (int nn = 0; nn < 4; ++nn)
#pragma unroll
      for (int mt = 0; mt < 2; ++mt)
#pragma unroll
        for (int i = 0; i < 4; ++i)
          yl[(nn * 16 + lr) * 33 + mt * 16 + g * 4 + i] = yacc[mt][cc * 4 + nn][i];
#pragma unroll
    for (int r2 = 0; r2 < 8; ++r2) {
      int c = r2 * 8 + row8;
      float4 v = *(const float4*)(yl + c * 33 + p4);
      *(float4*)(dst + ((size_t)b * CN + cc * 64 + c) * PN + p0 + p4) = v;
    }
  }
}

// ---- final reduction: out += sum of partials
__global__ void k_add(float* __restrict__ o, const float* __restrict__ a,
                      const float* __restrict__ bb, const float* __restrict__ c,
                      int np, int n4) {
  int i = blockIdx.x * blockDim.x + threadIdx.x;
  int stride = gridDim.x * blockDim.x;
  float4* o4 = (float4*)o;
  const float4* a4 = (const float4*)a;
  const float4* b4 = (const float4*)bb;
  const float4* c4 = (const float4*)c;
  for (; i < n4; i += stride) {
    float4 r = o4[i];
    float4 va = a4[i];
    r.x += va.x; r.y += va.y; r.z += va.z; r.w += va.w;
    if (np > 1) {
      float4 vb = b4[i];
      r.x += vb.x; r.y += vb.y; r.z += vb.z; r.w += vb.w;
      float4 vc = c4[i];
      r.x += vc.x; r.y += vc.y; r.z += vc.z; r.w += vc.w;
    }
    o4[i] = r;
  }
}

extern "C" void kernel_launch(void* const* d_in, const int* in_sizes, int n_in,
                              void* d_out, int out_size, void* d_ws, size_t ws_size,
                              hipStream_t stream) {
  const float* x = (const float*)d_in[0];
  const float* Wm = (const float*)d_in[1];
  const float* bias = (const float*)d_in[2];
  float* out = (float*)d_out;

  char* ws = (char*)d_ws;
  unsigned short* xnT = (unsigned short*)ws;                        // 8 MB  [B][P][C] bf16
  unsigned short* gxv = (unsigned short*)(ws + (size_t)8388608);    // 8 MB  [B][C][P] bf16
  float* mnorm = (float*)(ws + (size_t)16777216);                   // 64 KB [B][P] f32
  float* yp0 = (float*)(ws + (size_t)16842752);                     // 16 MB partials x3
  float* yp1 = yp0 + 4194304;
  float* yp2 = yp1 + 4194304;
  const size_t need4 = 16842752ULL + 3ULL * 16777216ULL;

  hipFuncSetAttribute(reinterpret_cast<const void*>(k_attn),
                      hipFuncAttributeMaxDynamicSharedMemorySize, 163840);

  k_nx<<<dim3(PN / 64, BN), 256, 0, stream>>>(x, mnorm, xnT);
  k_gx<<<dim3(PN / 64, CN / 64, BN), 256, 0, stream>>>(Wm, bias, xnT, mnorm, gxv);
  if (ws_size >= need4) {
    k_attn<<<dim3(256), 512, 163840, stream>>>(xnT, gxv, out, yp0, yp1, yp2, 2, (PN / 4) / QT);
    k_add<<<dim3(1024), 256, 0, stream>>>(out, yp0, yp1, yp2, 3, BN * CN * PN / 4);
  } else {
    k_attn<<<dim3(128), 512, 163840, stream>>>(xnT, gxv, out, yp0, yp0, yp0, 1, (PN / 2) / QT);
    k_add<<<dim3(1024), 256, 0, stream>>>(out, yp0, yp0, yp0, 1, BN * CN * PN / 4);
  }
}

// Round 6
// 122.436 us; speedup vs baseline: 6.4495x; 1.0038x over previous
//
#include <hip/hip_runtime.h>

#define BN 4
#define CN 256
#define PN 4096
#define QT 64
#define TSTR 264

typedef __attribute__((ext_vector_type(8))) short short8;
typedef __attribute__((ext_vector_type(8))) unsigned short ushort8;
typedef __attribute__((ext_vector_type(4))) float f32x4;
typedef __attribute__((ext_vector_type(2))) unsigned int u32x2;
typedef unsigned int u32;

__device__ __forceinline__ unsigned short f2bf(float f) {
  u32 u = __builtin_bit_cast(u32, f);
  return (unsigned short)((u + 0x7fffu + ((u >> 16) & 1u)) >> 16);
}

__device__ __forceinline__ void async_copy16(const void* g, void* l) {
  __builtin_amdgcn_global_load_lds((const __attribute__((address_space(1))) u32*)g,
                                   (__attribute__((address_space(3))) u32*)l, 16, 0, 0);
}

// ---- fused: per 64-pixel block, compute channel norm + write xnT[b][p][c] bf16
__global__ __launch_bounds__(256) void k_nx(const float* __restrict__ x,
                                            float* __restrict__ mnorm,
                                            unsigned short* __restrict__ xnT) {
  __shared__ unsigned short tl[64 * TSTR];
  __shared__ float red[4][64];
  const int b = blockIdx.y, p0 = blockIdx.x * 64;
  const int tid = threadIdx.x;
  const int tp = tid & 63, cg = tid >> 6;
  const float* xp = x + ((size_t)b * CN + cg * 64) * PN + p0 + tp;
  float v[64];
  float ss = 0.f;
#pragma unroll
  for (int i = 0; i < 64; ++i) {
    v[i] = xp[(size_t)i * PN];
    ss += v[i] * v[i];
  }
  red[cg][tp] = ss;
  __syncthreads();
  float nrm = sqrtf(red[0][tp] + red[1][tp] + red[2][tp] + red[3][tp]);
  float mn = fmaxf(nrm, 1e-8f);
  float rn = 1.f / mn;
  if (cg == 0) mnorm[b * PN + p0 + tp] = mn;
  unsigned int* tl32 = (unsigned int*)tl;
#pragma unroll
  for (int j = 0; j < 32; ++j) {
    unsigned int w = (unsigned int)f2bf(v[2 * j] * rn) |
                     ((unsigned int)f2bf(v[2 * j + 1] * rn) << 16);
    tl32[tp * (TSTR / 2) + cg * 32 + j] = w;
  }
  __syncthreads();
  unsigned short* xd = xnT + ((size_t)b * PN + p0) * CN;
  const int row = tid >> 2, qc = tid & 3;
#pragma unroll
  for (int i = 0; i < 8; ++i) {
    ushort8 o = *(const ushort8*)(tl + row * TSTR + i * 32 + qc * 8);
    *(ushort8*)(xd + (size_t)row * CN + i * 32 + qc * 8) = o;
  }
}

// ---- gxv[b][c][q] = bf16( (W @ xn)[c][q] * mnorm[q] + bias[c] )
__global__ void k_gx(const float* __restrict__ Wm, const float* __restrict__ bias,
                     const unsigned short* __restrict__ xnT, const float* __restrict__ mnorm,
                     unsigned short* __restrict__ gxv) {
  int b = blockIdx.z;
  int m0 = blockIdx.y * 64;
  int q0 = blockIdx.x * 64;
  int tid = threadIdx.x;
  int wave = tid >> 6, lane = tid & 63;
  int lr = lane & 15, g = lane >> 4;

  short8 af[8];
  {
    const float* wr = Wm + (size_t)(m0 + wave * 16 + lr) * CN;
#pragma unroll
    for (int k = 0; k < 8; ++k) {
      const float* ap = wr + k * 32 + g * 8;
      short8 a;
#pragma unroll
      for (int j = 0; j < 8; ++j) a[j] = (short)f2bf(ap[j]);
      af[k] = a;
    }
  }
  f32x4 acc[4];
#pragma unroll
  for (int n = 0; n < 4; ++n) acc[n] = (f32x4){0.f, 0.f, 0.f, 0.f};

  const unsigned short* xb = xnT + (size_t)b * PN * CN;
#pragma unroll
  for (int n = 0; n < 4; ++n) {
    const unsigned short* bp = xb + (size_t)(q0 + n * 16 + lr) * CN + g * 8;
#pragma unroll
    for (int k = 0; k < 8; ++k) {
      short8 bf = *(const short8*)(bp + k * 32);
      acc[n] = __builtin_amdgcn_mfma_f32_16x16x32_bf16(af[k], bf, acc[n], 0, 0, 0);
    }
  }
#pragma unroll
  for (int n = 0; n < 4; ++n) {
    int q = q0 + n * 16 + lr;
    float mn = mnorm[b * PN + q];
#pragma unroll
    for (int i = 0; i < 4; ++i) {
      int c = m0 + wave * 16 + g * 4 + i;
      float v = acc[n][i] * mn + bias[c];
      gxv[((size_t)b * CN + c) * PN + q] = f2bf(v);
    }
  }
}

// ---- fused attention: 8-wave WG, M=32 rows/wave, QT=64, 160KB LDS.
// Fragment-major LDS: each 1024B block = one MFMA fragment, laid out lane*16.
// LDS map: [0,64K)=buf0 (K 32 frags | V 32 frags), [64K,128K)=buf1, [128K,160K)=S (4K/wave).
extern __shared__ char smem[];

__global__ __launch_bounds__(512, 2) void k_attn(const unsigned short* __restrict__ xnT,
                                                 const unsigned short* __restrict__ gxv,
                                                 float* __restrict__ d0, float* __restrict__ d1,
                                                 float* __restrict__ d2, float* __restrict__ d3,
                                                 int lq, int ntiles) {
  const int fid = blockIdx.x;
  const int b = fid & 3;
  const int qs = (fid >> 2) & ((1 << lq) - 1);
  const int pblk = fid >> (2 + lq);
  const int tid = threadIdx.x;
  const int wave = tid >> 6, lane = tid & 63, lr = lane & 15, g = lane >> 4;
  const int qbase = qs * (PN >> lq);
  const int p0 = pblk * 256 + wave * 32;
  float* dst = (qs == 0) ? d0 : (qs == 1) ? d1 : (qs == 2) ? d2 : d3;

  const char* xbc = (const char*)xnT + (size_t)b * PN * 512;
  const char* vbc = (const char*)gxv + (size_t)b * CN * PN * 2;

  // per-lane DMA source constants (fragment-major gather; dest is linear ldst)
  // K frag (nt=j, k=w): lane l -> global (q0+nt*16+(l&15))*512 + k*64 + (l>>4)*16
  const int kofs = (lane & 15) * 512 + (lane >> 4) * 16 + wave * 64;
  // V frag (kk=j>>1, n2=(j&1)*8+w): lane l -> (n2*16+(l&15))*8192 + (q0+kk*32+(l>>4)*8)*2
  const int vofs = wave * 131072 + (lane & 15) * 8192 + (lane >> 4) * 16;
  const int ldst = tid * 16;
  const int lane16 = lane * 16;
  // S write base: frag-linear scatter for D[q][p] of swapped QK^T
  const int swb = lr * 16 + (g >> 1) * 256 + (g & 1) * 8;

  // hoist Q fragments (32 p-rows x 256 ch); layout doubles as B-operand (col=lr=p)
  short8 qf[2][8];
#pragma unroll
  for (int mt = 0; mt < 2; ++mt) {
    const char* qp = xbc + (size_t)(p0 + mt * 16 + lr) * 512 + g * 16;
#pragma unroll
    for (int k = 0; k < 8; ++k) qf[mt][k] = *(const short8*)(qp + k * 64);
  }

  f32x4 yacc[2][16];
#pragma unroll
  for (int mt = 0; mt < 2; ++mt)
#pragma unroll
    for (int n = 0; n < 16; ++n) yacc[mt][n] = (f32x4){0.f, 0.f, 0.f, 0.f};

  auto issue_L = [&](int t) {
    char* kb = smem + (t & 1) * 65536;
    char* vb = kb + 32768;
    const int q0 = qbase + t * QT;
    const char* kg = xbc + (size_t)q0 * 512 + kofs;
    const char* vg = vbc + (size_t)q0 * 2 + vofs;
#pragma unroll
    for (int j = 0; j < 4; ++j) async_copy16(kg + j * 8192, kb + ldst + j * 8192);
    async_copy16(vg, vb + ldst);
    async_copy16(vg + 1048576, vb + ldst + 8192);
    async_copy16(vg + 64, vb + ldst + 16384);
    async_copy16(vg + 1048576 + 64, vb + ldst + 24576);
  };

  char* Sme = smem + 131072 + wave * 4096;
  char* Sw = Sme + swb;

  auto compute = [&](int buf) {
    const char* kb = smem + buf * 65536;
    const char* vb = kb + 32768;
    __builtin_amdgcn_s_setprio(1);
    // --- swapped QK^T: D[q][p] = mfma(A=K, B=Q); frag-linear reads
    f32x4 sacc[4][2];
#pragma unroll
    for (int nt = 0; nt < 4; ++nt)
#pragma unroll
      for (int mt = 0; mt < 2; ++mt) sacc[nt][mt] = (f32x4){0.f, 0.f, 0.f, 0.f};
#pragma unroll
    for (int nh = 0; nh < 2; ++nh) {
#pragma unroll
      for (int k = 0; k < 8; ++k) {
        short8 kf0 = *(const short8*)(kb + ((2 * nh) * 8 + k) * 1024 + lane16);
        short8 kf1 = *(const short8*)(kb + ((2 * nh + 1) * 8 + k) * 1024 + lane16);
        sacc[2 * nh][0] = __builtin_amdgcn_mfma_f32_16x16x32_bf16(kf0, qf[0][k], sacc[2 * nh][0], 0, 0, 0);
        sacc[2 * nh][1] = __builtin_amdgcn_mfma_f32_16x16x32_bf16(kf0, qf[1][k], sacc[2 * nh][1], 0, 0, 0);
        sacc[2 * nh + 1][0] = __builtin_amdgcn_mfma_f32_16x16x32_bf16(kf1, qf[0][k], sacc[2 * nh + 1][0], 0, 0, 0);
        sacc[2 * nh + 1][1] = __builtin_amdgcn_mfma_f32_16x16x32_bf16(kf1, qf[1][k], sacc[2 * nh + 1][1], 0, 0, 0);
      }
    }
    // --- relu^2 -> bf16 pack -> frag-linear S (one b64 write per (nt,mt))
#pragma unroll
    for (int nt = 0; nt < 4; ++nt)
#pragma unroll
      for (int mt = 0; mt < 2; ++mt) {
        f32x4 s = sacc[nt][mt];
        float a0 = fmaxf(s[0], 0.f); a0 *= a0;
        float a1 = fmaxf(s[1], 0.f); a1 *= a1;
        float a2 = fmaxf(s[2], 0.f); a2 *= a2;
        float a3 = fmaxf(s[3], 0.f); a3 *= a3;
        u32x2 w;
        w[0] = (u32)f2bf(a0) | ((u32)f2bf(a1) << 16);
        w[1] = (u32)f2bf(a2) | ((u32)f2bf(a3) << 16);
        *(u32x2*)(Sw + mt * 2048 + (nt >> 1) * 1024 + (nt & 1) * 512) = w;
      }
    // --- PV: Y[32p][256c] += S[32x64] @ V[64q][256c]; all reads frag-linear
#pragma unroll
    for (int kk = 0; kk < 2; ++kk) {
      short8 pa0 = *(const short8*)(Sme + kk * 1024 + lane16);
      short8 pa1 = *(const short8*)(Sme + 2048 + kk * 1024 + lane16);
#pragma unroll
      for (int n2 = 0; n2 < 16; ++n2) {
        short8 vf = *(const short8*)(vb + (kk * 16 + n2) * 1024 + lane16);
        yacc[0][n2] = __builtin_amdgcn_mfma_f32_16x16x32_bf16(pa0, vf, yacc[0][n2], 0, 0, 0);
        yacc[1][n2] = __builtin_amdgcn_mfma_f32_16x16x32_bf16(pa1, vf, yacc[1][n2], 0, 0, 0);
      }
    }
    __builtin_amdgcn_s_setprio(0);
  };

  // pipeline: dbuf, issue t+1 after barrier of t; vmcnt drain covered by prior compute body
  issue_L(0);
  for (int t = 0; t < ntiles; ++t) {
    asm volatile("s_waitcnt vmcnt(0)" ::: "memory");
    __builtin_amdgcn_s_barrier();
    if (t + 1 < ntiles) issue_L(t + 1);
    compute(t & 1);
  }
  __builtin_amdgcn_s_barrier();

  // ---- epilogue: per-wave LDS transpose (16KB region each) for coalesced [c][p] stores
  // yacc[mt][n2][i] = y[p = p0 + mt*16 + g*4+i][c = n2*16 + lr]
  float* yl = (float*)(smem + wave * 16384);
  const int row8 = lane >> 3, p4 = (lane & 7) << 2;
#pragma unroll
  for (int cc = 0; cc < 4; ++cc) {
#pragma unroll
    for (int nn = 0; nn < 4; ++nn)
#pragma unroll
      for (int mt = 0; mt < 2; ++mt)
#pragma unroll
        for (int i = 0; i < 4; ++i)
          yl[(nn * 16 + lr) * 33 + mt * 16 + g * 4 + i] = yacc[mt][cc * 4 + nn][i];
#pragma unroll
    for (int r2 = 0; r2 < 8; ++r2) {
      int c = r2 * 8 + row8;
      float4 v = *(const float4*)(yl + c * 33 + p4);
      *(float4*)(dst + ((size_t)b * CN + cc * 64 + c) * PN + p0 + p4) = v;
    }
  }
}

// ---- final reduction: out += sum of partials
__global__ void k_add(float* __restrict__ o, const float* __restrict__ a,
                      const float* __restrict__ bb, const float* __restrict__ c,
                      int np, int n4) {
  int i = blockIdx.x * blockDim.x + threadIdx.x;
  int stride = gridDim.x * blockDim.x;
  float4* o4 = (float4*)o;
  const float4* a4 = (const float4*)a;
  const float4* b4 = (const float4*)bb;
  const float4* c4 = (const float4*)c;
  for (; i < n4; i += stride) {
    float4 r = o4[i];
    float4 va = a4[i];
    r.x += va.x; r.y += va.y; r.z += va.z; r.w += va.w;
    if (np > 1) {
      float4 vb = b4[i];
      r.x += vb.x; r.y += vb.y; r.z += vb.z; r.w += vb.w;
      float4 vc = c4[i];
      r.x += vc.x; r.y += vc.y; r.z += vc.z; r.w += vc.w;
    }
    o4[i] = r;
  }
}

extern "C" void kernel_launch(void* const* d_in, const int* in_sizes, int n_in,
                              void* d_out, int out_size, void* d_ws, size_t ws_size,
                              hipStream_t stream) {
  const float* x = (const float*)d_in[0];
  const float* Wm = (const float*)d_in[1];
  const float* bias = (const float*)d_in[2];
  float* out = (float*)d_out;

  char* ws = (char*)d_ws;
  unsigned short* xnT = (unsigned short*)ws;                        // 8 MB  [B][P][C] bf16
  unsigned short* gxv = (unsigned short*)(ws + (size_t)8388608);    // 8 MB  [B][C][P] bf16
  float* mnorm = (float*)(ws + (size_t)16777216);                   // 64 KB [B][P] f32
  float* yp0 = (float*)(ws + (size_t)16842752);                     // 16 MB partials x3
  float* yp1 = yp0 + 4194304;
  float* yp2 = yp1 + 4194304;
  const size_t need4 = 16842752ULL + 3ULL * 16777216ULL;

  hipFuncSetAttribute(reinterpret_cast<const void*>(k_attn),
                      hipFuncAttributeMaxDynamicSharedMemorySize, 163840);

  k_nx<<<dim3(PN / 64, BN), 256, 0, stream>>>(x, mnorm, xnT);
  k_gx<<<dim3(PN / 64, CN / 64, BN), 256, 0, stream>>>(Wm, bias, xnT, mnorm, gxv);
  if (ws_size >= need4) {
    k_attn<<<dim3(256), 512, 163840, stream>>>(xnT, gxv, out, yp0, yp1, yp2, 2, (PN / 4) / QT);
    k_add<<<dim3(1024), 256, 0, stream>>>(out, yp0, yp1, yp2, 3, BN * CN * PN / 4);
  } else {
    k_attn<<<dim3(128), 512, 163840, stream>>>(xnT, gxv, out, yp0, yp0, yp0, 1, (PN / 2) / QT);
    k_add<<<dim3(1024), 256, 0, stream>>>(out, yp0, yp0, yp0, 1, BN * CN * PN / 4);
  }
}

// Round 7
// 114.237 us; speedup vs baseline: 6.9124x; 1.0718x over previous
//
#include <hip/hip_runtime.h>

#define BN 4
#define CN 256
#define PN 4096
#define QT 64
#define TSTR 264

typedef __attribute__((ext_vector_type(8))) short short8;
typedef __attribute__((ext_vector_type(8))) unsigned short ushort8;
typedef __attribute__((ext_vector_type(4))) float f32x4;
typedef __attribute__((ext_vector_type(2))) unsigned int u32x2;
typedef unsigned int u32;

__device__ __forceinline__ unsigned short f2bf(float f) {
  u32 u = __builtin_bit_cast(u32, f);
  return (unsigned short)((u + 0x7fffu + ((u >> 16) & 1u)) >> 16);
}

__device__ __forceinline__ void async_copy16(const void* g, void* l) {
  __builtin_amdgcn_global_load_lds((const __attribute__((address_space(1))) u32*)g,
                                   (__attribute__((address_space(3))) u32*)l, 16, 0, 0);
}

// ---- fused: per 64-pixel block, compute channel norm + write xnT[b][p][c] bf16
__global__ __launch_bounds__(256) void k_nx(const float* __restrict__ x,
                                            float* __restrict__ mnorm,
                                            unsigned short* __restrict__ xnT) {
  __shared__ unsigned short tl[64 * TSTR];
  __shared__ float red[4][64];
  const int b = blockIdx.y, p0 = blockIdx.x * 64;
  const int tid = threadIdx.x;
  const int tp = tid & 63, cg = tid >> 6;
  const float* xp = x + ((size_t)b * CN + cg * 64) * PN + p0 + tp;
  float v[64];
  float ss = 0.f;
#pragma unroll
  for (int i = 0; i < 64; ++i) {
    v[i] = xp[(size_t)i * PN];
    ss += v[i] * v[i];
  }
  red[cg][tp] = ss;
  __syncthreads();
  float nrm = sqrtf(red[0][tp] + red[1][tp] + red[2][tp] + red[3][tp]);
  float mn = fmaxf(nrm, 1e-8f);
  float rn = 1.f / mn;
  if (cg == 0) mnorm[b * PN + p0 + tp] = mn;
  unsigned int* tl32 = (unsigned int*)tl;
#pragma unroll
  for (int j = 0; j < 32; ++j) {
    unsigned int w = (unsigned int)f2bf(v[2 * j] * rn) |
                     ((unsigned int)f2bf(v[2 * j + 1] * rn) << 16);
    tl32[tp * (TSTR / 2) + cg * 32 + j] = w;
  }
  __syncthreads();
  unsigned short* xd = xnT + ((size_t)b * PN + p0) * CN;
  const int row = tid >> 2, qc = tid & 3;
#pragma unroll
  for (int i = 0; i < 8; ++i) {
    ushort8 o = *(const ushort8*)(tl + row * TSTR + i * 32 + qc * 8);
    *(ushort8*)(xd + (size_t)row * CN + i * 32 + qc * 8) = o;
  }
}

// ---- gxv[b][c][q] = bf16( (W @ xn)[c][q] * mnorm[q] + bias[c] )
__global__ void k_gx(const float* __restrict__ Wm, const float* __restrict__ bias,
                     const unsigned short* __restrict__ xnT, const float* __restrict__ mnorm,
                     unsigned short* __restrict__ gxv) {
  int b = blockIdx.z;
  int m0 = blockIdx.y * 64;
  int q0 = blockIdx.x * 64;
  int tid = threadIdx.x;
  int wave = tid >> 6, lane = tid & 63;
  int lr = lane & 15, g = lane >> 4;

  short8 af[8];
  {
    const float* wr = Wm + (size_t)(m0 + wave * 16 + lr) * CN;
#pragma unroll
    for (int k = 0; k < 8; ++k) {
      const float* ap = wr + k * 32 + g * 8;
      short8 a;
#pragma unroll
      for (int j = 0; j < 8; ++j) a[j] = (short)f2bf(ap[j]);
      af[k] = a;
    }
  }
  f32x4 acc[4];
#pragma unroll
  for (int n = 0; n < 4; ++n) acc[n] = (f32x4){0.f, 0.f, 0.f, 0.f};

  const unsigned short* xb = xnT + (size_t)b * PN * CN;
#pragma unroll
  for (int n = 0; n < 4; ++n) {
    const unsigned short* bp = xb + (size_t)(q0 + n * 16 + lr) * CN + g * 8;
#pragma unroll
    for (int k = 0; k < 8; ++k) {
      short8 bf = *(const short8*)(bp + k * 32);
      acc[n] = __builtin_amdgcn_mfma_f32_16x16x32_bf16(af[k], bf, acc[n], 0, 0, 0);
    }
  }
#pragma unroll
  for (int n = 0; n < 4; ++n) {
    int q = q0 + n * 16 + lr;
    float mn = mnorm[b * PN + q];
#pragma unroll
    for (int i = 0; i < 4; ++i) {
      int c = m0 + wave * 16 + g * 4 + i;
      float v = acc[n][i] * mn + bias[c];
      gxv[((size_t)b * CN + c) * PN + q] = f2bf(v);
    }
  }
}

// ---- fused attention: 8-wave WG, M=32 rows/wave, QT=64, 160KB LDS.
// Fragment-major LDS: each 1024B block = one MFMA fragment, laid out lane*16.
// LDS map: [0,64K)=buf0 (K 32 frags | V 32 frags), [64K,128K)=buf1, [128K,160K)=S (4K/wave).
// Schedule: counted vmcnt(4) (K and V tracked separately), two barriers/tile,
// K(t+1) issued under QKT(t), V(t+1) issued under PV(t). Never vmcnt(0) mid-loop.
extern __shared__ char smem[];

__global__ __launch_bounds__(512, 2) void k_attn(const unsigned short* __restrict__ xnT,
                                                 const unsigned short* __restrict__ gxv,
                                                 float* __restrict__ d0, float* __restrict__ d1,
                                                 float* __restrict__ d2, float* __restrict__ d3,
                                                 int lq, int ntiles) {
  const int fid = blockIdx.x;
  const int b = fid & 3;
  const int qs = (fid >> 2) & ((1 << lq) - 1);
  const int pblk = fid >> (2 + lq);
  const int tid = threadIdx.x;
  const int wave = tid >> 6, lane = tid & 63, lr = lane & 15, g = lane >> 4;
  const int qbase = qs * (PN >> lq);
  const int p0 = pblk * 256 + wave * 32;
  float* dst = (qs == 0) ? d0 : (qs == 1) ? d1 : (qs == 2) ? d2 : d3;

  const char* xbc = (const char*)xnT + (size_t)b * PN * 512;
  const char* vbc = (const char*)gxv + (size_t)b * CN * PN * 2;

  // per-lane DMA source constants (fragment-major gather; dest is linear ldst)
  const int kofs = (lane & 15) * 512 + (lane >> 4) * 16 + wave * 64;
  const int vofs = wave * 131072 + (lane & 15) * 8192 + (lane >> 4) * 16;
  const int ldst = tid * 16;
  const int lane16 = lane * 16;
  // S write base: frag-linear scatter for D[q][p] of swapped QK^T
  const int swb = lr * 16 + (g >> 1) * 256 + (g & 1) * 8;

  auto issue_K = [&](int t) {
    char* kb = smem + (t & 1) * 65536;
    const char* kg = xbc + (size_t)(qbase + t * QT) * 512 + kofs;
#pragma unroll
    for (int j = 0; j < 4; ++j) async_copy16(kg + j * 8192, kb + ldst + j * 8192);
  };
  auto issue_V = [&](int t) {
    char* vb = smem + (t & 1) * 65536 + 32768;
    const char* vg = vbc + (size_t)(qbase + t * QT) * 2 + vofs;
    async_copy16(vg, vb + ldst);
    async_copy16(vg + 1048576, vb + ldst + 8192);
    async_copy16(vg + 64, vb + ldst + 16384);
    async_copy16(vg + 1048576 + 64, vb + ldst + 24576);
  };

  // start DMA before the Q hoist so it overlaps
  issue_K(0);
  issue_V(0);

  // hoist Q fragments (32 p-rows x 256 ch); layout doubles as B-operand (col=lr=p)
  short8 qf[2][8];
#pragma unroll
  for (int mt = 0; mt < 2; ++mt) {
    const char* qp = xbc + (size_t)(p0 + mt * 16 + lr) * 512 + g * 16;
#pragma unroll
    for (int k = 0; k < 8; ++k) qf[mt][k] = *(const short8*)(qp + k * 64);
  }

  f32x4 yacc[2][16];
#pragma unroll
  for (int mt = 0; mt < 2; ++mt)
#pragma unroll
    for (int n = 0; n < 16; ++n) yacc[mt][n] = (f32x4){0.f, 0.f, 0.f, 0.f};

  char* Sme = smem + 131072 + wave * 4096;
  char* Sw = Sme + swb;

  for (int t = 0; t < ntiles; ++t) {
    const char* kb = smem + (t & 1) * 65536;
    const char* vb = kb + 32768;
    // K(t) ready (V(t) still in flight)
    asm volatile("s_waitcnt vmcnt(4)" ::: "memory");
    __builtin_amdgcn_s_barrier();
    if (t + 1 < ntiles) issue_K(t + 1);

    // --- swapped QK^T: D[q][p] = mfma(A=K, B=Q); frag-linear reads
    f32x4 sacc[4][2];
#pragma unroll
    for (int nt = 0; nt < 4; ++nt)
#pragma unroll
      for (int mt = 0; mt < 2; ++mt) sacc[nt][mt] = (f32x4){0.f, 0.f, 0.f, 0.f};
    __builtin_amdgcn_s_setprio(1);
#pragma unroll
    for (int nh = 0; nh < 2; ++nh) {
#pragma unroll
      for (int k = 0; k < 8; ++k) {
        short8 kf0 = *(const short8*)(kb + ((2 * nh) * 8 + k) * 1024 + lane16);
        short8 kf1 = *(const short8*)(kb + ((2 * nh + 1) * 8 + k) * 1024 + lane16);
        sacc[2 * nh][0] = __builtin_amdgcn_mfma_f32_16x16x32_bf16(kf0, qf[0][k], sacc[2 * nh][0], 0, 0, 0);
        sacc[2 * nh][1] = __builtin_amdgcn_mfma_f32_16x16x32_bf16(kf0, qf[1][k], sacc[2 * nh][1], 0, 0, 0);
        sacc[2 * nh + 1][0] = __builtin_amdgcn_mfma_f32_16x16x32_bf16(kf1, qf[0][k], sacc[2 * nh + 1][0], 0, 0, 0);
        sacc[2 * nh + 1][1] = __builtin_amdgcn_mfma_f32_16x16x32_bf16(kf1, qf[1][k], sacc[2 * nh + 1][1], 0, 0, 0);
      }
    }
    __builtin_amdgcn_s_setprio(0);

    // --- relu^2 -> v_cvt_pk_bf16_f32 -> frag-linear S (one b64 write per (nt,mt))
#pragma unroll
    for (int nt = 0; nt < 4; ++nt)
#pragma unroll
      for (int mt = 0; mt < 2; ++mt) {
        f32x4 s = sacc[nt][mt];
        float a0 = fmaxf(s[0], 0.f); a0 *= a0;
        float a1 = fmaxf(s[1], 0.f); a1 *= a1;
        float a2 = fmaxf(s[2], 0.f); a2 *= a2;
        float a3 = fmaxf(s[3], 0.f); a3 *= a3;
        u32x2 w;
        asm("v_cvt_pk_bf16_f32 %0, %1, %2" : "=v"(w[0]) : "v"(a0), "v"(a1));
        asm("v_cvt_pk_bf16_f32 %0, %1, %2" : "=v"(w[1]) : "v"(a2), "v"(a3));
        *(u32x2*)(Sw + mt * 2048 + (nt >> 1) * 1024 + (nt & 1) * 512) = w;
      }

    // V(t) ready (K(t+1) still in flight)
    if (t + 1 < ntiles) {
      asm volatile("s_waitcnt vmcnt(4)" ::: "memory");
    } else {
      asm volatile("s_waitcnt vmcnt(0)" ::: "memory");
    }
    __builtin_amdgcn_s_barrier();
    if (t + 1 < ntiles) issue_V(t + 1);

    // --- PV: Y[32p][256c] += S[32x64] @ V[64q][256c]; all reads frag-linear
#pragma unroll
    for (int kk = 0; kk < 2; ++kk) {
      short8 pa0 = *(const short8*)(Sme + kk * 1024 + lane16);
      short8 pa1 = *(const short8*)(Sme + 2048 + kk * 1024 + lane16);
      __builtin_amdgcn_s_setprio(1);
#pragma unroll
      for (int n2 = 0; n2 < 16; ++n2) {
        short8 vf = *(const short8*)(vb + (kk * 16 + n2) * 1024 + lane16);
        yacc[0][n2] = __builtin_amdgcn_mfma_f32_16x16x32_bf16(pa0, vf, yacc[0][n2], 0, 0, 0);
        yacc[1][n2] = __builtin_amdgcn_mfma_f32_16x16x32_bf16(pa1, vf, yacc[1][n2], 0, 0, 0);
      }
      __builtin_amdgcn_s_setprio(0);
    }
  }
  __builtin_amdgcn_s_barrier();

  // ---- epilogue: per-wave LDS transpose (16KB region each) for coalesced [c][p] stores
  // yacc[mt][n2][i] = y[p = p0 + mt*16 + g*4+i][c = n2*16 + lr]
  float* yl = (float*)(smem + wave * 16384);
  const int row8 = lane >> 3, p4 = (lane & 7) << 2;
#pragma unroll
  for (int cc = 0; cc < 4; ++cc) {
#pragma unroll
    for (int nn = 0; nn < 4; ++nn)
#pragma unroll
      for (int mt = 0; mt < 2; ++mt)
#pragma unroll
        for (int i = 0; i < 4; ++i)
          yl[(nn * 16 + lr) * 33 + mt * 16 + g * 4 + i] = yacc[mt][cc * 4 + nn][i];
#pragma unroll
    for (int r2 = 0; r2 < 8; ++r2) {
      int c = r2 * 8 + row8;
      float4 v = *(const float4*)(yl + c * 33 + p4);
      *(float4*)(dst + ((size_t)b * CN + cc * 64 + c) * PN + p0 + p4) = v;
    }
  }
}

// ---- final reduction: out += sum of partials
__global__ void k_add(float* __restrict__ o, const float* __restrict__ a,
                      const float* __restrict__ bb, const float* __restrict__ c,
                      int np, int n4) {
  int i = blockIdx.x * blockDim.x + threadIdx.x;
  int stride = gridDim.x * blockDim.x;
  float4* o4 = (float4*)o;
  const float4* a4 = (const float4*)a;
  const float4* b4 = (const float4*)bb;
  const float4* c4 = (const float4*)c;
  for (; i < n4; i += stride) {
    float4 r = o4[i];
    float4 va = a4[i];
    r.x += va.x; r.y += va.y; r.z += va.z; r.w += va.w;
    if (np > 1) {
      float4 vb = b4[i];
      r.x += vb.x; r.y += vb.y; r.z += vb.z; r.w += vb.w;
      float4 vc = c4[i];
      r.x += vc.x; r.y += vc.y; r.z += vc.z; r.w += vc.w;
    }
    o4[i] = r;
  }
}

extern "C" void kernel_launch(void* const* d_in, const int* in_sizes, int n_in,
                              void* d_out, int out_size, void* d_ws, size_t ws_size,
                              hipStream_t stream) {
  const float* x = (const float*)d_in[0];
  const float* Wm = (const float*)d_in[1];
  const float* bias = (const float*)d_in[2];
  float* out = (float*)d_out;

  char* ws = (char*)d_ws;
  unsigned short* xnT = (unsigned short*)ws;                        // 8 MB  [B][P][C] bf16
  unsigned short* gxv = (unsigned short*)(ws + (size_t)8388608);    // 8 MB  [B][C][P] bf16
  float* mnorm = (float*)(ws + (size_t)16777216);                   // 64 KB [B][P] f32
  float* yp0 = (float*)(ws + (size_t)16842752);                     // 16 MB partials x3
  float* yp1 = yp0 + 4194304;
  float* yp2 = yp1 + 4194304;
  const size_t need4 = 16842752ULL + 3ULL * 16777216ULL;

  hipFuncSetAttribute(reinterpret_cast<const void*>(k_attn),
                      hipFuncAttributeMaxDynamicSharedMemorySize, 163840);

  k_nx<<<dim3(PN / 64, BN), 256, 0, stream>>>(x, mnorm, xnT);
  k_gx<<<dim3(PN / 64, CN / 64, BN), 256, 0, stream>>>(Wm, bias, xnT, mnorm, gxv);
  if (ws_size >= need4) {
    k_attn<<<dim3(256), 512, 163840, stream>>>(xnT, gxv, out, yp0, yp1, yp2, 2, (PN / 4) / QT);
    k_add<<<dim3(1024), 256, 0, stream>>>(out, yp0, yp1, yp2, 3, BN * CN * PN / 4);
  } else {
    k_attn<<<dim3(128), 512, 163840, stream>>>(xnT, gxv, out, yp0, yp0, yp0, 1, (PN / 2) / QT);
    k_add<<<dim3(1024), 256, 0, stream>>>(out, yp0, yp0, yp0, 1, BN * CN * PN / 4);
  }
}